// Round 6
// baseline (5367.592 us; speedup 1.0000x reference)
//
#include <hip/hip_runtime.h>
#include <stdint.h>

// LSTM persistent kernel, round 11. 256 WGs x 512 thr, 1 WG/CU.
//
// Round-10 post-mortem: xg-split neutral (phase-1 win eaten by phase-2 +
// 4.2x bank conflicts from the new hbuf stride). The structural cost is
// the exchange: WRITE_SIZE 327MB = out 67MB + publishes 260MB -> agent
// publishes WRITE THROUGH to the memory side; publish->poll RT is
// HBM/MALL-class, twice serialized per step (~4000 cyc/step of the 5860).
//
// Round-11: L2-local exchange via RUNTIME same-XCD quartets. No inline asm.
//   1) Each WG reads XCC_ID (__builtin_amdgcn_s_getreg, m09-verified reg;
//      builtin avoids rounds-6..8's asm-parser failure), registers via
//      device atomicAdd, crosses a one-shot global barrier (all 256 WGs
//      resident - rounds 0-5 already depend on this), and quartets form
//      WITHIN an XCD. Roles (p,q) assigned dynamically; any permutation is
//      valid. Garbage XCC values still give a valid partition.
//   2) Same-XCD quartets exchange via volatile 8B ld/st (volatile loads
//      compile with L1-bypass -> serviced at the shared per-XCD L2;
//      stores write through L1 to L2). A bounded TWO-BEAT self-test (beat
//      2 re-polls a line beat 1 would have cached -> detects both
//      non-bypassing loads and wrong grouping) + an UNCONDITIONALLY POSTED
//      agent-scope consensus picks fast/slow per quartet. Failures
//      degrade to round-10's proven agent-atomic path; nothing can hang.
//   3) hbuf TRANSPOSE: h dword dl stored at phys ((dl>>2)&3)*32 +
//      (dl>>4)*4 + (dl&3) -> phase-1 ds_read_b128 hits all 8 bank-groups
//      (was 4-way conflicted); out-proj 8-way -> 4-way.
//
// Exchange protocol per quartet unchanged: SELF-VALIDATING 8B entries
// {hi: tag=t+1, lo: 2 x fp16}; ring-2 slots + exact tags; harness poison
// 0xAAAAAAAA never matches tags 1..2048. Publish phase 1, full
// __syncthreads, poll phase 2 (round-9 lesson: keep this schedule).

#define T_SEQ 2048
#define BATCH 128
#define IN_D  128
#define HID   256
#define OUTD  64

typedef _Float16 half2_t __attribute__((ext_vector_type(2)));

__device__ __forceinline__ float dot2f(uint32_t w, uint32_t h, float acc) {
#if __has_builtin(__builtin_amdgcn_fdot2)
  return __builtin_amdgcn_fdot2(__builtin_bit_cast(half2_t, w),
                                __builtin_bit_cast(half2_t, h), acc, false);
#else
  half2_t a = __builtin_bit_cast(half2_t, w);
  half2_t b = __builtin_bit_cast(half2_t, h);
  return acc + (float)a[0] * (float)b[0] + (float)a[1] * (float)b[1];
#endif
}

__device__ __forceinline__ uint32_t pack2(float a, float b) {
  union { _Float16 h[2]; uint32_t u; } u_;
  u_.h[0] = (_Float16)a; u_.h[1] = (_Float16)b;
  return u_.u;
}

// ---- slow-path primitives: round-5/10 proven agent-scope atomics ----
__device__ __forceinline__ uint64_t ld64_ag(const uint64_t* p) {
  return __hip_atomic_load(p, __ATOMIC_RELAXED, __HIP_MEMORY_SCOPE_AGENT);
}
__device__ __forceinline__ void st64_ag(uint64_t* p, uint64_t v) {
  __hip_atomic_store(p, v, __ATOMIC_RELAXED, __HIP_MEMORY_SCOPE_AGENT);
}
__device__ __forceinline__ uint32_t ld32_ag(const uint32_t* p) {
  return __hip_atomic_load(p, __ATOMIC_RELAXED, __HIP_MEMORY_SCOPE_AGENT);
}

// ---- fast-path primitives: volatile -> L1-bypassing load / L2 store ----
__device__ __forceinline__ uint64_t ld64_vol(const uint64_t* p) {
  return *(const volatile uint64_t*)p;
}
__device__ __forceinline__ void st64_vol(uint64_t* p, uint64_t v) {
  *(volatile uint64_t*)p = v;
}

// load 8 consecutive fp32 weights -> uint4 of 8 fp16 (4 packed pairs)
__device__ __forceinline__ uint4 loadW8(const float* __restrict__ pw) {
  const float4 a = *(const float4*)pw;
  const float4 b = *(const float4*)(pw + 4);
  uint4 r;
  r.x = pack2(a.x, a.y); r.y = pack2(a.z, a.w);
  r.z = pack2(b.x, b.y); r.w = pack2(b.z, b.w);
  return r;
}

__device__ __forceinline__ float sigm(float v) { return 1.f / (1.f + __expf(-v)); }
__device__ __forceinline__ float tanhx(float v) {
  float a = fabsf(v);
  float e = __expf(2.f * a);
  float r = 1.f - 2.f / (e + 1.f);
  return v < 0.f ? -r : r;
}

// transposed hbuf address: logical in-row dword dl -> physical dword
__device__ __forceinline__ int hphys(int dl) {
  return ((dl >> 2) & 3) * 32 + ((dl >> 4) << 2) + (dl & 3);
}

#define D4(Wv, Hv, A)                       \
  A = dot2f(Wv.x, Hv.x, A);                 \
  A = dot2f(Wv.y, Hv.y, A);                 \
  A = dot2f(Wv.z, Hv.z, A);                 \
  A = dot2f(Wv.w, Hv.w, A);

#define PIN4(v) asm volatile("" : "+v"(v.x), "+v"(v.y), "+v"(v.z), "+v"(v.w));

// xg(step) partials from xring slot base (in dwords): 64 dot2, all threads
#define XG_ALL(slotbase)                                                     \
  {                                                                          \
    const uint4* xp0 = (const uint4*)(xring + (slotbase)) + ks * 2;          \
    const uint4* xp1 = (const uint4*)(xring + (slotbase) + 64) + ks * 2;     \
    const uint4 xa = xp0[0], xb = xp0[1];                                    \
    const uint4 xc = xp1[0], xd = xp1[1];                                    \
    axg00 = 0.f; axg10 = 0.f; axg20 = 0.f; axg30 = 0.f;                      \
    axg01 = 0.f; axg11 = 0.f; axg21 = 0.f; axg31 = 0.f;                      \
    D4(X0_0, xa, axg00) D4(X0_1, xb, axg00)                                  \
    D4(X1_0, xa, axg10) D4(X1_1, xb, axg10)                                  \
    D4(X2_0, xa, axg20) D4(X2_1, xb, axg20)                                  \
    D4(X3_0, xa, axg30) D4(X3_1, xb, axg30)                                  \
    D4(X0_0, xc, axg01) D4(X0_1, xd, axg01)                                  \
    D4(X1_0, xc, axg11) D4(X1_1, xd, axg11)                                  \
    D4(X2_0, xc, axg21) D4(X2_1, xd, axg21)                                  \
    D4(X3_0, xc, axg31) D4(X3_1, xd, axg31)                                  \
  }

#define MAGB 0x600DD00Dull
#define MAGC 0xC0015EEDull
// s_getreg imm encoding: id=20 (HW_REG_XCC_ID) | offset 0<<6 | (32-1)<<11
#define XCC_GETREG_IMM 63508

__global__ __launch_bounds__(512, 2)
void lstm_persist(const float* __restrict__ x,   const float* __restrict__ Wih,
                  const float* __restrict__ Whh, const float* __restrict__ bih,
                  const float* __restrict__ bhh, const float* __restrict__ Wout,
                  const float* __restrict__ bout_g, float* __restrict__ out,
                  uint64_t* exch, uint64_t* hdr)
{
  // hbuf: 2 rows x 128 dw (TRANSPOSED layout, see hphys).
  // xring: 2 slots x 2 rows x 64 dw.
  __shared__ alignas(16) uint32_t hbuf[2 * 128];
  __shared__ alignas(16) uint32_t xring[2 * 2 * 64];
  __shared__ int sh_p, sh_q, sh_fast;

  const int tid = threadIdx.x;
  const int w   = blockIdx.x;

  // ---- prologue: registration -> roles -> scope self-test (tid 0) ----
  if (tid == 0) {
    int p, q, fast = 0;
    if (hdr) {
      uint32_t* h32  = (uint32_t*)hdr;      // [0..7]=cnt, [8]=arrive, [9]=leftover
      uint64_t* test = hdr + 8;             // 256 x 8B self-test slots
      uint64_t* cons = hdr + 8 + 256;       // 256 x 8B consensus slots
      uint32_t xcc = __builtin_amdgcn_s_getreg(XCC_GETREG_IMM) & 7u;
      const int s = (int)atomicAdd(&h32[xcc], 1u);
      __threadfence();
      atomicAdd(&h32[8], 1u);
      while (ld32_ag(&h32[8]) < 256u) { }
      uint32_t c[8]; uint32_t tq = 0;
      for (int i = 0; i < 8; ++i) { c[i] = ld32_ag(&h32[i]); tq += c[i] >> 2; }
      if ((uint32_t)(s >> 2) < (c[xcc] >> 2)) {      // complete same-XCD quartet
        uint32_t before = 0;
        for (uint32_t i = 0; i < xcc; ++i) before += c[i] >> 2;
        p = (int)(before + (uint32_t)(s >> 2)); q = s & 3;
      } else {                                        // leftover: mixed quartet
        uint32_t li = atomicAdd(&h32[9], 1u);
        p = (int)(tq + (li >> 2)); q = (int)(li & 3);
      }
      // two-beat volatile self-test (bounded): beat 2 re-polls a line that
      // a non-bypassing L1 would have cached at beat 1 -> timeout -> slow.
      int ok = 1;
      st64_vol(&test[p * 4 + q], (MAGB << 32) | 1ull);
      for (int m = 0; m < 4 && ok; ++m) {
        if (m == q) continue;
        int spins = 0; uint64_t e;
        do {
          e = ld64_vol(&test[p * 4 + m]);
          if (++spins > 32768) { ok = 0; break; }
        } while ((e >> 32) != MAGB);
      }
      st64_vol(&test[p * 4 + q], (MAGB << 32) | 2ull);
      for (int m = 0; m < 4 && ok; ++m) {
        if (m == q) continue;
        int spins = 0; uint64_t e;
        do {
          e = ld64_vol(&test[p * 4 + m]);
          if (++spins > 32768) { ok = 0; break; }
        } while (e != ((MAGB << 32) | 2ull));
      }
      // consensus: ALWAYS posted, agent scope (proven path) -> no deadlock.
      st64_ag(&cons[p * 4 + q], (MAGC << 32) | (uint64_t)(ok & 1));
      fast = ok;
      for (int m = 0; m < 4; ++m) {
        if (m == q) continue;
        uint64_t e;
        do { e = ld64_ag(&cons[p * 4 + m]); } while ((e >> 32) != MAGC);
        fast &= (int)(e & 1);
      }
    } else {
      p = w & 63; q = w >> 6; fast = 0;               // no workspace: static
    }
    sh_p = p; sh_q = q; sh_fast = fast;
  }
  __syncthreads();
  const int p = sh_p, q = sh_q, fastf = sh_fast;

  const int jj  = tid >> 3;               // 0..63 hidden unit within quarter
  const int ks  = tid & 7;                // 0..7 K-slice
  const int rbase = (q << 6) + jj;        // gate-row base within a gate block
  const int role  = (q << 6) | p;         // exchange role id

  // ---- weights: 24 named uint4 (96 dwords), pinned to VGPRs
  uint4 H0_0, H0_1, H0_2, H0_3, X0_0, X0_1;
  uint4 H1_0, H1_1, H1_2, H1_3, X1_0, X1_1;
  uint4 H2_0, H2_1, H2_2, H2_3, X2_0, X2_1;
  uint4 H3_0, H3_1, H3_2, H3_3, X3_0, X3_1;
#define LOADG(g)                                                 \
  { const int row = (g) * HID + rbase;                           \
    const float* ph = Whh + (size_t)row * HID + (ks << 5);       \
    H##g##_0 = loadW8(ph);      H##g##_1 = loadW8(ph + 8);       \
    H##g##_2 = loadW8(ph + 16); H##g##_3 = loadW8(ph + 24);      \
    const float* px = Wih + (size_t)row * IN_D + (ks << 4);      \
    X##g##_0 = loadW8(px);      X##g##_1 = loadW8(px + 8); }
  LOADG(0) LOADG(1) LOADG(2) LOADG(3)
#undef LOADG
  PIN4(H0_0) PIN4(H0_1) PIN4(H0_2) PIN4(H0_3) PIN4(X0_0) PIN4(X0_1)
  PIN4(H1_0) PIN4(H1_1) PIN4(H1_2) PIN4(H1_3) PIN4(X1_0) PIN4(X1_1)
  PIN4(H2_0) PIN4(H2_1) PIN4(H2_2) PIN4(H2_3) PIN4(X2_0) PIN4(X2_1)
  PIN4(H3_0) PIN4(H3_1) PIN4(H3_2) PIN4(H3_3) PIN4(X3_0) PIN4(X3_1)

  // ---- gate biases (used by ks<2 lanes)
  float b0 = bih[0 * HID + rbase] + bhh[0 * HID + rbase];
  float b1 = bih[1 * HID + rbase] + bhh[1 * HID + rbase];
  float b2 = bih[2 * HID + rbase] + bhh[2 * HID + rbase];
  float b3 = bih[3 * HID + rbase] + bhh[3 * HID + rbase];

  // ---- out-projection: thread (oo,r,os): o = q*16+oo, K-slice os*16..+16
  const int oo = tid >> 5, orow = (tid >> 4) & 1, os = tid & 15;
  uint4 woA, woB;
  {
    const float* wo = Wout + (size_t)((q << 4) + oo) * HID + (os << 4);
    const float4 v0 = *(const float4*)(wo + 0), v1 = *(const float4*)(wo + 4);
    const float4 v2 = *(const float4*)(wo + 8), v3 = *(const float4*)(wo + 12);
    woA.x = pack2(v0.x, v0.y); woA.y = pack2(v0.z, v0.w);
    woA.z = pack2(v1.x, v1.y); woA.w = pack2(v1.z, v1.w);
    woB.x = pack2(v2.x, v2.y); woB.y = pack2(v2.z, v2.w);
    woB.z = pack2(v3.x, v3.y); woB.w = pack2(v3.z, v3.w);
  }
  PIN4(woA) PIN4(woB)
  const float bo = bout_g[(q << 4) + oo];
  // out-proj physical read addrs (transposed hbuf): granules os*2, os*2+1
  const int oadr0 = orow * 128 + (((os * 2)     & 3) << 5) + ((os >> 1) << 2);
  const int oadr1 = orow * 128 + (((os * 2 + 1) & 3) << 5) + ((os >> 1) << 2);

  // ---- init: h=0; xring slot0 = x(0), slot1 = x(1)
  if (tid < 256) hbuf[tid] = 0u;
  if (tid < 128) {
    const int row = tid >> 6, cc = tid & 63;
    const float2 xv = *(const float2*)(x + (size_t)(2 * p + row) * IN_D + 2 * cc);
    xring[row * 64 + cc] = pack2(xv.x, xv.y);
  } else if (tid < 256) {
    const int i = tid - 128, row = i >> 6, cc = i & 63;
    const float2 xv = *(const float2*)(x + (size_t)BATCH * IN_D +
                                       (size_t)(2 * p + row) * IN_D + 2 * cc);
    xring[128 + row * 64 + cc] = pack2(xv.x, xv.y);
  }
  float c = 0.f;
  __syncthreads();

  // poller geometry (threads 64..255 consume the 3 partner quarters)
  const int pi  = tid - 64;
  const int pqq = pi >> 6, pl = pi & 63;
  const int pqp = pqq + (pqq >= q);            // partner quarter != q
  const int prole = (pqp << 6) | p;
  const int dep_adr = (pl >> 5) * 128 + hphys((pqp << 5) + (pl & 31));

  // prologue: xg partials for step 0 (from xring slot 0)
  float axg00, axg10, axg20, axg30, axg01, axg11, axg21, axg31;
  XG_ALL(0)

  for (int t = 0; t <= T_SEQ; ++t) {
    uint32_t xn = 0;
    uint32_t packed = 0;
    // ---------------- phase 1 (critical: W_hh*h only) ----------------
    if (t < T_SEQ) {
      if (tid >= 256 && tid < 384 && (t + 2) < T_SEQ) {
        const int row = (tid - 256) >> 6, cc = (tid - 256) & 63;
        const float2 xv = *(const float2*)(x + (size_t)(t + 2) * BATCH * IN_D +
                                           (size_t)(2 * p + row) * IN_D + 2 * cc);
        xn = pack2(xv.x, xv.y);
      }
      float a00 = axg00, a10 = axg10, a20 = axg20, a30 = axg30;
      float a01 = axg01, a11 = axg11, a21 = axg21, a31 = axg31;
      {
        const uint32_t* hb = hbuf;                               // row 0
        const uint4 h0 = *(const uint4*)(hb +       (ks << 2));
        const uint4 h1 = *(const uint4*)(hb +  32 + (ks << 2));
        const uint4 h2 = *(const uint4*)(hb +  64 + (ks << 2));
        const uint4 h3 = *(const uint4*)(hb +  96 + (ks << 2));
        D4(H0_0, h0, a00) D4(H0_1, h1, a00) D4(H0_2, h2, a00) D4(H0_3, h3, a00)
        D4(H1_0, h0, a10) D4(H1_1, h1, a10) D4(H1_2, h2, a10) D4(H1_3, h3, a10)
        D4(H2_0, h0, a20) D4(H2_1, h1, a20) D4(H2_2, h2, a20) D4(H2_3, h3, a20)
        D4(H3_0, h0, a30) D4(H3_1, h1, a30) D4(H3_2, h2, a30) D4(H3_3, h3, a30)
      }
      {
        const uint32_t* hb = hbuf + 128;                         // row 1
        const uint4 h0 = *(const uint4*)(hb +       (ks << 2));
        const uint4 h1 = *(const uint4*)(hb +  32 + (ks << 2));
        const uint4 h2 = *(const uint4*)(hb +  64 + (ks << 2));
        const uint4 h3 = *(const uint4*)(hb +  96 + (ks << 2));
        D4(H0_0, h0, a01) D4(H0_1, h1, a01) D4(H0_2, h2, a01) D4(H0_3, h3, a01)
        D4(H1_0, h0, a11) D4(H1_1, h1, a11) D4(H1_2, h2, a11) D4(H1_3, h3, a11)
        D4(H2_0, h0, a21) D4(H2_1, h1, a21) D4(H2_2, h2, a21) D4(H2_3, h3, a21)
        D4(H3_0, h0, a31) D4(H3_1, h1, a31) D4(H3_2, h2, a31) D4(H3_3, h3, a31)
      }
      // select-tree reduction over the 8 ks lanes (16 shuffles)
      float u0, u1, u2, u3;
      {
        const int r = ks & 1;
        float t0, t1;
        t0 = a00 + __shfl_xor(a00, 1, 64); t1 = a01 + __shfl_xor(a01, 1, 64);
        u0 = r ? t1 : t0;
        t0 = a10 + __shfl_xor(a10, 1, 64); t1 = a11 + __shfl_xor(a11, 1, 64);
        u1 = r ? t1 : t0;
        t0 = a20 + __shfl_xor(a20, 1, 64); t1 = a21 + __shfl_xor(a21, 1, 64);
        u2 = r ? t1 : t0;
        t0 = a30 + __shfl_xor(a30, 1, 64); t1 = a31 + __shfl_xor(a31, 1, 64);
        u3 = r ? t1 : t0;
      }
      u0 += __shfl_xor(u0, 2, 64); u0 += __shfl_xor(u0, 4, 64);
      u1 += __shfl_xor(u1, 2, 64); u1 += __shfl_xor(u1, 4, 64);
      u2 += __shfl_xor(u2, 2, 64); u2 += __shfl_xor(u2, 4, 64);
      u3 += __shfl_xor(u3, 2, 64); u3 += __shfl_xor(u3, 4, 64);
      if (ks < 2) {   // lane ks holds all 4 gates for row r=ks
        const int r = ks;
        const float iv = sigm(b0 + u0), fv = sigm(b1 + u1);
        const float gv = tanhx(b2 + u2), ov = sigm(b3 + u3);
        c = fv * c + iv * gv;
        const float hn = ov * tanhx(c);
        union { _Float16 h; unsigned short u; } cv; cv.h = (_Float16)hn;
        const uint32_t mine  = cv.u;
        const uint32_t other = (uint32_t)(unsigned short)__shfl_xor((int)mine, 8, 64);
        if (!(jj & 1)) {
          packed = mine | (other << 16);   // h units (jj, jj+1) of row r
          const uint64_t entry = ((uint64_t)(uint32_t)(t + 1) << 32) | packed;
          uint64_t* dst =
              exch + (((size_t)role << 7) | ((t & 1) << 6)) + (r << 5) + (jj >> 1);
          if (fastf) st64_vol(dst, entry); else st64_ag(dst, entry);
        }
      }
    }
    if (t >= 1) {  // out-projection for step t-1 from h(t-1) still in hbuf
      const uint4 h0 = *(const uint4*)(hbuf + oadr0);
      const uint4 h1 = *(const uint4*)(hbuf + oadr1);
      float oa = 0.f;
      oa = dot2f(woA.x, h0.x, oa); oa = dot2f(woA.y, h0.y, oa);
      oa = dot2f(woA.z, h0.z, oa); oa = dot2f(woA.w, h0.w, oa);
      oa = dot2f(woB.x, h1.x, oa); oa = dot2f(woB.y, h1.y, oa);
      oa = dot2f(woB.z, h1.z, oa); oa = dot2f(woB.w, h1.w, oa);
      oa += __shfl_xor(oa, 1, 64); oa += __shfl_xor(oa, 2, 64);
      oa += __shfl_xor(oa, 4, 64); oa += __shfl_xor(oa, 8, 64);
      if (os == 0)
        out[((size_t)(t - 1) * BATCH + 2 * p + orow) * OUTD + (q << 4) + oo] = oa + bo;
    }
    __syncthreads();  // B1 (full drain: pushes the publish out promptly)
    // ---------------- phase 2 (xg(t+1) overlaps the poll stall) ----------
    if (t < T_SEQ) {
      if (ks < 2 && !(jj & 1))  // write own h pair into hbuf (transposed)
        hbuf[ks * 128 + hphys((q << 5) + (jj >> 1))] = packed;
      if (tid >= 256 && tid < 384 && (t + 2) < T_SEQ)
        xring[((t & 1) << 7) + (((tid - 256) >> 6) << 6) + ((tid - 256) & 63)] = xn;
      if (t + 1 < T_SEQ)
        XG_ALL(((t + 1) & 1) << 7)   // xg partials for next step, all threads
      if (tid >= 64 && tid < 256) {  // consume 3 partner quarters
        const uint64_t* src =
            exch + (((size_t)prole << 7) | ((t & 1) << 6)) + pl;
        const uint32_t want = (uint32_t)(t + 1);
        uint64_t e;
        if (fastf) {
          do { e = ld64_vol(src); } while ((uint32_t)(e >> 32) != want);
        } else {
          do { e = ld64_ag(src);  } while ((uint32_t)(e >> 32) != want);
        }
        hbuf[dep_adr] = (uint32_t)e;
      }
    }
    __syncthreads();  // B2: hbuf fully assembled for step t+1
  }
}

extern "C" void kernel_launch(void* const* d_in, const int* in_sizes, int n_in,
                              void* d_out, int out_size, void* d_ws, size_t ws_size,
                              hipStream_t stream) {
  (void)in_sizes; (void)n_in; (void)out_size;
  const float* x    = (const float*)d_in[0];
  const float* Wih  = (const float*)d_in[1];
  const float* Whh  = (const float*)d_in[2];
  const float* bih  = (const float*)d_in[3];
  const float* bhh  = (const float*)d_in[4];
  const float* Wout = (const float*)d_in[5];
  const float* bout = (const float*)d_in[6];
  float* out = (float*)d_out;

  // exch ring: 256 roles x 2 slots x 64 entries x 8B = 256 KiB.
  // hdr (after ring): cnt[8]+arrive+leftover (u32), test[256], cons[256].
  const size_t RING_BYTES = 256u * 1024u;
  const size_t HDR_BYTES  = 8u * 1024u;
  uint64_t* exch = (uint64_t*)d_ws;
  uint64_t* hdr  = nullptr;
  if (ws_size >= RING_BYTES + HDR_BYTES) {
    hdr = exch + (RING_BYTES / 8);
    // Zero the hdr each dispatch (stream op, capture-legal; the harness's
    // own reset uses hipMemsetAsync). Registration counters REQUIRE zeros.
    hipMemsetAsync((void*)hdr, 0, HDR_BYTES, stream);
  }
  // Ring needs no memset: poison 0xAAAAAAAA never matches tags 1..2048.

  hipLaunchKernelGGL(lstm_persist, dim3(256), dim3(512), 0, stream,
                     x, Wih, Whh, bih, bhh, Wout, bout, out, exch, hdr);
}